// Round 15
// baseline (147.008 us; speedup 1.0000x reference)
//
#include <hip/hip_runtime.h>

typedef unsigned short u16;
typedef unsigned int u32;
typedef unsigned long long u64;
typedef float f32x4 __attribute__((ext_vector_type(4)));
typedef __bf16 bf16x8 __attribute__((ext_vector_type(8)));

// f32 -> bf16 round-to-nearest-even (scalar)
__device__ __forceinline__ u16 f2bf(float f) {
  unsigned u = __float_as_uint(f);
  unsigned r = u + 0x7fffu + ((u >> 16) & 1u);
  return (u16)(r >> 16);
}
// packed f32 pair -> 2x bf16 in one u32 (lo = first arg)
__device__ __forceinline__ u32 cvt_pk_bf16(float lo, float hi) {
  u32 r;
  asm("v_cvt_pk_bf16_f32 %0, %1, %2" : "=v"(r) : "v"(lo), "v"(hi));
  return r;
}
// hardware 2^x
__device__ __forceinline__ float exp2_hw(float x) {
  float r;
  asm("v_exp_f32 %0, %1" : "=v"(r) : "v"(x));
  return r;
}
__device__ __forceinline__ bf16x8 f32x8_to_bf16x8(float4 a, float4 b) {
  union { u32 u[4]; bf16x8 v; } t;
  t.u[0] = cvt_pk_bf16(a.x, a.y);
  t.u[1] = cvt_pk_bf16(a.z, a.w);
  t.u[2] = cvt_pk_bf16(b.x, b.y);
  t.u[3] = cvt_pk_bf16(b.z, b.w);
  return t.v;
}
// async global->LDS, 16B per lane; dest = uniform base + lane*16 (HW rule)
__device__ __forceinline__ void gload_lds16(const void* g, u16* l) {
  __builtin_amdgcn_global_load_lds(
      (const __attribute__((address_space(1))) unsigned int*)g,
      (__attribute__((address_space(3))) unsigned int*)l, 16, 0, 0);
}

// 1/sqrt(32) * log2(e)  — softmax scale folded with exp->exp2 conversion
#define QSCALE 0.25513936f

// ---------------------------------------------------------------------------
// proj_kv: KV-only (R7-verified z-split path, Q moved into attn).
// grid 256, block 256. z=0: K + V ch 0..127; z=1: V ch 128..255.
// Layouts: Kt[b][s][32], Vb[b][ch][4096].
// ---------------------------------------------------------------------------
__global__ __launch_bounds__(256) void proj_kv(
    const float* __restrict__ x, const float* __restrict__ Wk, const float* __restrict__ bk,
    const float* __restrict__ Wv, const float* __restrict__ bv, u16* __restrict__ Kt,
    u16* __restrict__ Vb) {
  __shared__ __align__(16) u16 xs[16384];  // pooled [64 s][256 c] bf16, swizzled (32KB)
  const int tid = threadIdx.x;
  const int lane = tid & 63, w = tid >> 6;
  const int l15 = lane & 15, l4 = lane >> 4;
  const int bi = blockIdx.x;
  const int b = bi >> 7, r2 = bi & 127;
  const int sy = r2 >> 1, z = r2 & 1;
  const int mb = z * 8;
  const float* xb = x + (size_t)b * 256 * 16384;
  const f32x4 zero = {0.f, 0.f, 0.f, 0.f};

#pragma unroll
  for (int rr = 0; rr < 4; ++rr) {
    int c = rr * 64 + (tid >> 2);
    int f4base = (tid & 3) * 8;
    const float* r0 = xb + (size_t)c * 16384 + (size_t)sy * 256;
#pragma unroll
    for (int u = 0; u < 8; ++u) {
      int jj = f4base + u;
      float4 a = *reinterpret_cast<const float4*>(r0 + jj * 4);
      float4 d = *reinterpret_cast<const float4*>(r0 + 128 + jj * 4);
      float p0 = (a.x + a.y + d.x + d.y) * 0.25f;
      float p1 = (a.z + a.w + d.z + d.w) * 0.25f;
      int s0 = jj * 2;
      *reinterpret_cast<u16*>((char*)xs + (s0 + 0) * 512 + (((c >> 3) ^ ((s0 + 0) & 7)) * 16) + (c & 7) * 2) = f2bf(p0);
      *reinterpret_cast<u16*>((char*)xs + (s0 + 1) * 512 + (((c >> 3) ^ ((s0 + 1) & 7)) * 16) + (c & 7) * 2) = f2bf(p1);
    }
  }
  __syncthreads();

  f32x4 acc[10];
#pragma unroll
  for (int m = 0; m < 10; ++m) acc[m] = zero;
  const int sl = w * 16 + l15;
#pragma unroll
  for (int k = 0; k < 8; ++k) {
    bf16x8 bf = *reinterpret_cast<const bf16x8*>((char*)xs + sl * 512 +
                                                 (((k * 4 + l4) ^ (sl & 7)) * 16));
    if (z == 0) {
#pragma unroll
      for (int m = 0; m < 2; ++m) {
        const float* wr = Wk + (size_t)(m * 16 + l15) * 256 + k * 32 + l4 * 8;
        float4 fa = *reinterpret_cast<const float4*>(wr);
        float4 fb = *reinterpret_cast<const float4*>(wr + 4);
        acc[m] = __builtin_amdgcn_mfma_f32_16x16x32_bf16(f32x8_to_bf16x8(fa, fb), bf, acc[m], 0, 0, 0);
      }
    }
#pragma unroll
    for (int mm = 0; mm < 8; ++mm) {
      const float* wr = Wv + (size_t)((mb + mm) * 16 + l15) * 256 + k * 32 + l4 * 8;
      float4 fa = *reinterpret_cast<const float4*>(wr);
      float4 fb = *reinterpret_cast<const float4*>(wr + 4);
      acc[2 + mm] = __builtin_amdgcn_mfma_f32_16x16x32_bf16(f32x8_to_bf16x8(fa, fb), bf, acc[2 + mm], 0, 0, 0);
    }
  }
  if (z == 0) {
#pragma unroll
    for (int m = 0; m < 2; ++m) {
      int oc0 = m * 16 + l4 * 4;
      u32 p0 = cvt_pk_bf16(acc[m][0] + bk[oc0], acc[m][1] + bk[oc0 + 1]);
      u32 p1 = cvt_pk_bf16(acc[m][2] + bk[oc0 + 2], acc[m][3] + bk[oc0 + 3]);
      u16* dst = Kt + ((size_t)b * 4096 + sy * 64 + sl) * 32 + oc0;
      *reinterpret_cast<u32*>(dst) = p0;
      *reinterpret_cast<u32*>(dst + 2) = p1;
    }
  }
#pragma unroll
  for (int mm = 0; mm < 8; ++mm) {
#pragma unroll
    for (int r = 0; r < 4; ++r) {
      int oc = (mb + mm) * 16 + l4 * 4 + r;
      Vb[((size_t)b * 256 + oc) * 4096 + sy * 64 + sl] = f2bf(acc[2 + mm][r] + bv[oc]);
    }
  }
}

// ---------------------------------------------------------------------------
// attn v15 = R14 (verified: 80KB, one barrier/iter, clamp, immediate P-write)
// + fused Q-projection prologue (R6-verified code). LDS aliasing (time-
// disjoint, barrier-ordered):
//   prologue: xt (32KB) + wqs (16KB) alias v_lds; q_lds (4KB) aliases
//   p_lds[1] (bytes 8192..12288). qfr hoisted to regs before any loop
//   P-write can touch p_lds[1]. Loop identical to R14.
// ---------------------------------------------------------------------------
__global__ __launch_bounds__(256, 2) void attn_kernel(
    const float* __restrict__ x, const float* __restrict__ Wq, const float* __restrict__ bq,
    const u16* __restrict__ Kt, const u16* __restrict__ Vb, const float* __restrict__ gamma,
    float* __restrict__ out) {
  __shared__ __align__(16) u16 p_lds[2][64 * 64];   // 16KB dbuf P [tok][key swz]
  __shared__ __align__(16) u16 v_lds[2][256 * 64];  // 64KB dbuf V [ch][key swz]

  const int tid = threadIdx.x;
  const int lane = tid & 63, w = tid >> 6;
  const int l15 = lane & 15, l4 = lane >> 4, l7 = l15 & 7;
  const int raw = blockIdx.x;               // 0..511
  const int xcd = raw & 7, loc = raw >> 3;  // loc 0..63
  const int b = xcd >> 2;
  const int tt = (xcd & 3) * 64 + loc;      // tok-tile 0..255
  const int t0 = tt * 64;
  const f32x4 zero = {0.f, 0.f, 0.f, 0.f};

  const char* Kpc = (const char*)(Kt + (size_t)b * 4096 * 32);
  const char* Vpc = (const char*)(Vb + (size_t)b * 256 * 4096);

  // ============ fused Q projection (R6-verified; aliased LDS) ============
  {
    u16* xt = (u16*)v_lds;            // [64 t][256 c] bf16, swizzled (32KB)
    u16* wqs = (u16*)v_lds + 16384;   // [32 oc][256 c] bf16, swz, pre-scaled (16KB)
    u16* qlds = (u16*)p_lds + 4096;   // [64 t][32 oc] (4KB, in p_lds[1])
    const float* xp = x + (size_t)b * 256 * 16384 + t0;

    // stage Wq (scale folded)
    for (int i = tid; i < 4096; i += 256) {
      int oc = i >> 7, c0 = (i & 127) * 2;
      float2 f = *reinterpret_cast<const float2*>(Wq + oc * 256 + c0);
      u32 pk = cvt_pk_bf16(f.x * QSCALE, f.y * QSCALE);
      *reinterpret_cast<u32*>((char*)wqs + oc * 512 + (((c0 >> 3) ^ (oc & 7)) * 16) +
                              (c0 & 7) * 2) = pk;
    }
    // stage x tile transposed: xt[t][c]
#pragma unroll
    for (int rr = 0; rr < 4; ++rr) {
      int c = rr * 64 + (tid >> 2);
      int tch = (tid & 3) * 16;
      const float* src = xp + (size_t)c * 16384 + tch;
#pragma unroll
      for (int u = 0; u < 4; ++u) {
        float4 f = *reinterpret_cast<const float4*>(src + u * 4);
        int t = tch + u * 4;
        *reinterpret_cast<u16*>((char*)xt + (t + 0) * 512 + (((c >> 3) ^ ((t + 0) & 7)) * 16) + (c & 7) * 2) = f2bf(f.x);
        *reinterpret_cast<u16*>((char*)xt + (t + 1) * 512 + (((c >> 3) ^ ((t + 1) & 7)) * 16) + (c & 7) * 2) = f2bf(f.y);
        *reinterpret_cast<u16*>((char*)xt + (t + 2) * 512 + (((c >> 3) ^ ((t + 2) & 7)) * 16) + (c & 7) * 2) = f2bf(f.z);
        *reinterpret_cast<u16*>((char*)xt + (t + 3) * 512 + (((c >> 3) ^ ((t + 3) & 7)) * 16) + (c & 7) * 2) = f2bf(f.w);
      }
    }
    __syncthreads();

    // GEMM: wave w owns 16 toks (tl), m = 2 oc-tiles, k = 8
    f32x4 qacc[2] = {zero, zero};
    const int tl = w * 16 + l15;
#pragma unroll
    for (int k = 0; k < 8; ++k) {
      bf16x8 bfx = *reinterpret_cast<const bf16x8*>((char*)xt + tl * 512 +
                                                    (((k * 4 + l4) ^ (tl & 7)) * 16));
#pragma unroll
      for (int m = 0; m < 2; ++m) {
        int oc = m * 16 + l15;
        bf16x8 af = *reinterpret_cast<const bf16x8*>((char*)wqs + oc * 512 +
                                                     (((k * 4 + l4) ^ (oc & 7)) * 16));
        qacc[m] = __builtin_amdgcn_mfma_f32_16x16x32_bf16(af, bfx, qacc[m], 0, 0, 0);
      }
    }
    // bias (scale-folded) + packed store to q_lds[t][oc]
#pragma unroll
    for (int m = 0; m < 2; ++m) {
      int oc0 = m * 16 + l4 * 4;
      u32 p0 = cvt_pk_bf16(qacc[m][0] + bq[oc0] * QSCALE, qacc[m][1] + bq[oc0 + 1] * QSCALE);
      u32 p1 = cvt_pk_bf16(qacc[m][2] + bq[oc0 + 2] * QSCALE, qacc[m][3] + bq[oc0 + 3] * QSCALE);
      u16* dst = qlds + tl * 32 + oc0;
      *reinterpret_cast<u32*>(dst) = p0;
      *reinterpret_cast<u32*>(dst + 2) = p1;
    }
  }
  __syncthreads();  // Q-GEMM done: xt/wqs dead (v_lds reusable), qlds ready

  // ============ attention (R14 verbatim from here) ============
  // Q fragments hoisted to regs (reads p_lds[1] region BEFORE any P-write)
  bf16x8 qfr[4];
#pragma unroll
  for (int mt = 0; mt < 4; ++mt)
    qfr[mt] = *reinterpret_cast<const bf16x8*>((u16*)p_lds + 4096 +
                                               (mt * 16 + l15) * 32 + l4 * 8);

  const int key = w * 16 + l15;  // QK A-op row (wave's 16-key strip)
  const int pw_chunk = w * 2 + (l4 >> 1), pw_off = (l4 & 1) * 8;

  // ---- loop-invariant lane bases (valid: tok&7 == l7, ch&7 == l7) ----
  char* pA0 = (char*)p_lds + l15 * 128 + ((l4 ^ l7) * 16);
  char* pA1 = (char*)p_lds + l15 * 128 + (((4 ^ l4) ^ l7) * 16);
  char* pW = (char*)p_lds + l15 * 128 + ((pw_chunk ^ l7) * 16) + pw_off;
  char* pV0 = (char*)v_lds + (w * 64 + l15) * 128 + ((l4 ^ l7) * 16);
  char* pV1 = (char*)v_lds + (w * 64 + l15) * 128 + (((4 ^ l4) ^ l7) * 16);

  // ---- staging: per-lane pre-swizzled source (linear dest == swz layout) ----
  const int sch = lane >> 3;         // sub-channel in 8-ch group
  const int skc = (lane & 7) ^ sch;  // source key-chunk
  const u32 vstg0 = (u32)(w * 64 + sch) * 8192 + (u32)skc * 16;  // i stride 65536
  u32 vstg = vstg0 + 128;                               // V(kt=1)
  u32 vok = 2 * 4096 + (u32)key * 64 + (u32)l4 * 16;    // K(kt=2)

  f32x4 acc[4][4] = {};  // [tok mt][ch nt] 64tok x 64ch quadrant
  float lsum[4] = {};

  // ---- prologue: DMA V(0)->buf0; QK(0)->p_lds[0]; kfrA = K(1) ----
#pragma unroll
  for (int i = 0; i < 8; ++i)
    gload_lds16(Vpc + vstg0 + i * 65536, (u16*)v_lds + (w * 8 + i) * 512);
  {
    bf16x8 k0 = *reinterpret_cast<const bf16x8*>(Kpc + ((size_t)key * 64 + l4 * 16));
#pragma unroll
    for (int mt = 0; mt < 4; ++mt) {
      f32x4 s = __builtin_amdgcn_mfma_f32_16x16x32_bf16(k0, qfr[mt], zero, 0, 0, 0);
      float p0 = exp2_hw(fminf(s[0], 28.f)), p1 = exp2_hw(fminf(s[1], 28.f));
      float p2 = exp2_hw(fminf(s[2], 28.f)), p3 = exp2_hw(fminf(s[3], 28.f));
      lsum[mt] += (p0 + p1) + (p2 + p3);
      *reinterpret_cast<u64*>(pW + mt * 2048) =
          (u64)cvt_pk_bf16(p0, p1) | ((u64)cvt_pk_bf16(p2, p3) << 32);
    }
  }
  bf16x8 kfrA = *reinterpret_cast<const bf16x8*>(Kpc + (4096 + (size_t)key * 64 + l4 * 16));
  bf16x8 kfrB;
  __syncthreads();  // drains V(0) DMA; P(0) visible; qfr reads complete

#define ATTN_ITER(KT, CUR, KC, KN)                                                        \
  {                                                                                       \
    /* DMA V(KT+1) -> vbuf[CUR^1] at TOP: full iteration of flight time */                \
    if ((KT) < 63) {                                                                      \
      _Pragma("unroll") for (int i = 0; i < 8; ++i)                                       \
          gload_lds16(Vpc + vstg + i * 65536,                                             \
                      (u16*)v_lds + (((CUR) ^ 1) * 16384) + (w * 8 + i) * 512);           \
      vstg += 128;                                                                        \
    }                                                                                     \
    /* ks=0 operand reads (latency hidden under QK/exp below) */                          \
    bf16x8 afr0[4], vfr0[4];                                                              \
    _Pragma("unroll") for (int mt = 0; mt < 4; ++mt)                                      \
        afr0[mt] = *reinterpret_cast<const bf16x8*>(pA0 + ((CUR)*8192 + mt * 2048));      \
    _Pragma("unroll") for (int nt = 0; nt < 4; ++nt)                                      \
        vfr0[nt] = *reinterpret_cast<const bf16x8*>(pV0 + ((CUR)*32768 + nt * 2048));     \
    /* QK(KT+1) + exp + IMMEDIATE packed b64 write P[CUR^1] */                            \
    if ((KT) < 63) {                                                                      \
      _Pragma("unroll") for (int mt = 0; mt < 4; ++mt) {                                  \
        f32x4 s = __builtin_amdgcn_mfma_f32_16x16x32_bf16(KC, qfr[mt], zero, 0, 0, 0);    \
        float p0 = exp2_hw(fminf(s[0], 28.f)), p1 = exp2_hw(fminf(s[1], 28.f));           \
        float p2 = exp2_hw(fminf(s[2], 28.f)), p3 = exp2_hw(fminf(s[3], 28.f));           \
        lsum[mt] += (p0 + p1) + (p2 + p3);                                                \
        *reinterpret_cast<u64*>(pW + (((CUR) ^ 1) * 8192 + mt * 2048)) =                  \
            (u64)cvt_pk_bf16(p0, p1) | ((u64)cvt_pk_bf16(p2, p3) << 32);                  \
      }                                                                                   \
      if ((KT) < 62) { KN = *reinterpret_cast<const bf16x8*>(Kpc + vok); vok += 4096; }   \
    }                                                                                     \
    /* PV(KT): two ks-halves, mt=4 x nt=4 */                                              \
    __builtin_amdgcn_s_setprio(1);                                                        \
    _Pragma("unroll") for (int mt = 0; mt < 4; ++mt)                                      \
      _Pragma("unroll") for (int nt = 0; nt < 4; ++nt)                                    \
        acc[mt][nt] =                                                                     \
            __builtin_amdgcn_mfma_f32_16x16x32_bf16(afr0[mt], vfr0[nt], acc[mt][nt], 0, 0, 0); \
    bf16x8 afr1[4], vfr1[4];                                                              \
    _Pragma("unroll") for (int mt = 0; mt < 4; ++mt)                                      \
        afr1[mt] = *reinterpret_cast<const bf16x8*>(pA1 + ((CUR)*8192 + mt * 2048));      \
    _Pragma("unroll") for (int nt = 0; nt < 4; ++nt)                                      \
        vfr1[nt] = *reinterpret_cast<const bf16x8*>(pV1 + ((CUR)*32768 + nt * 2048));     \
    _Pragma("unroll") for (int mt = 0; mt < 4; ++mt)                                      \
      _Pragma("unroll") for (int nt = 0; nt < 4; ++nt)                                    \
        acc[mt][nt] =                                                                     \
            __builtin_amdgcn_mfma_f32_16x16x32_bf16(afr1[mt], vfr1[nt], acc[mt][nt], 0, 0, 0); \
    __builtin_amdgcn_s_setprio(0);                                                        \
    __syncthreads();                                                                      \
  }

  for (int it = 0; it < 32; ++it) {
    ATTN_ITER(2 * it, 0, kfrA, kfrB)
    ATTN_ITER(2 * it + 1, 1, kfrB, kfrA)
  }
#undef ATTN_ITER

  // ---- row sums: reduce over l4 groups; lred aliased into dead v_lds ----
  float* lred = (float*)v_lds;  // [4 w][64 tok]
#pragma unroll
  for (int mt = 0; mt < 4; ++mt) {
    lsum[mt] += __shfl_xor(lsum[mt], 16, 64);
    lsum[mt] += __shfl_xor(lsum[mt], 32, 64);
  }
  if (l4 == 0) {
#pragma unroll
    for (int mt = 0; mt < 4; ++mt) lred[w * 64 + mt * 16 + l15] = lsum[mt];
  }
  __syncthreads();

  const float g = gamma[0];
  float linv[16];
#pragma unroll
  for (int mt = 0; mt < 4; ++mt)
#pragma unroll
    for (int r = 0; r < 4; ++r) {
      int tok = mt * 16 + l4 * 4 + r;
      linv[mt * 4 + r] =
          1.0f / (lred[tok] + lred[64 + tok] + lred[128 + tok] + lred[192 + tok]);
    }
  // ---- epilogue: out = gamma * acc / l + x ----
#pragma unroll
  for (int mt = 0; mt < 4; ++mt) {
#pragma unroll
    for (int nt = 0; nt < 4; ++nt) {
      int ch = w * 64 + nt * 16 + l15;
      size_t idx = ((size_t)(b * 256 + ch)) * 16384 + t0 + mt * 16 + l4 * 4;
      float4 xr = *reinterpret_cast<const float4*>(x + idx);
      float4 o;
      o.x = g * acc[mt][nt][0] * linv[mt * 4 + 0] + xr.x;
      o.y = g * acc[mt][nt][1] * linv[mt * 4 + 1] + xr.y;
      o.z = g * acc[mt][nt][2] * linv[mt * 4 + 2] + xr.z;
      o.w = g * acc[mt][nt][3] * linv[mt * 4 + 3] + xr.w;
      *reinterpret_cast<float4*>(out + idx) = o;
    }
  }
}

// ---------------------------------------------------------------------------
extern "C" void kernel_launch(void* const* d_in, const int* in_sizes, int n_in,
                              void* d_out, int out_size, void* d_ws, size_t ws_size,
                              hipStream_t stream) {
  const float* x = (const float*)d_in[0];
  const float* Wq = (const float*)d_in[1];
  const float* bq = (const float*)d_in[2];
  const float* Wk = (const float*)d_in[3];
  const float* bk = (const float*)d_in[4];
  const float* Wv = (const float*)d_in[5];
  const float* bv = (const float*)d_in[6];
  const float* gamma = (const float*)d_in[7];
  float* out = (float*)d_out;

  char* ws = (char*)d_ws;
  u16* Kt = (u16*)ws;                   // 512 KB: [2][4096][32]
  u16* Vb = (u16*)(ws + (512u << 10));  // 4 MB  : [2][256][4096]

  proj_kv<<<dim3(256), 256, 0, stream>>>(x, Wk, bk, Wv, bv, Kt, Vb);
  attn_kernel<<<dim3(512), 256, 0, stream>>>(x, Wq, bq, Kt, Vb, gamma, out);
}

// Round 16
// 126.488 us; speedup vs baseline: 1.1622x; 1.1622x over previous
//
#include <hip/hip_runtime.h>

typedef unsigned short u16;
typedef unsigned int u32;
typedef unsigned long long u64;
typedef float f32x4 __attribute__((ext_vector_type(4)));
typedef __bf16 bf16x8 __attribute__((ext_vector_type(8)));

// f32 -> bf16 round-to-nearest-even (scalar)
__device__ __forceinline__ u16 f2bf(float f) {
  unsigned u = __float_as_uint(f);
  unsigned r = u + 0x7fffu + ((u >> 16) & 1u);
  return (u16)(r >> 16);
}
// packed f32 pair -> 2x bf16 in one u32 (lo = first arg)
__device__ __forceinline__ u32 cvt_pk_bf16(float lo, float hi) {
  u32 r;
  asm("v_cvt_pk_bf16_f32 %0, %1, %2" : "=v"(r) : "v"(lo), "v"(hi));
  return r;
}
// hardware 2^x
__device__ __forceinline__ float exp2_hw(float x) {
  float r;
  asm("v_exp_f32 %0, %1" : "=v"(r) : "v"(x));
  return r;
}
__device__ __forceinline__ bf16x8 f32x8_to_bf16x8(float4 a, float4 b) {
  union { u32 u[4]; bf16x8 v; } t;
  t.u[0] = cvt_pk_bf16(a.x, a.y);
  t.u[1] = cvt_pk_bf16(a.z, a.w);
  t.u[2] = cvt_pk_bf16(b.x, b.y);
  t.u[3] = cvt_pk_bf16(b.z, b.w);
  return t.v;
}
// async global->LDS, 16B per lane; dest = uniform base + lane*16 (HW rule)
__device__ __forceinline__ void gload_lds16(const void* g, u16* l) {
  __builtin_amdgcn_global_load_lds(
      (const __attribute__((address_space(1))) unsigned int*)g,
      (__attribute__((address_space(3))) unsigned int*)l, 16, 0, 0);
}

// 1/sqrt(32) * log2(e)  — softmax scale folded with exp->exp2 conversion
#define QSCALE 0.25513936f

// ---------------------------------------------------------------------------
// proj_kernel (R7-verified): blocks 0..255 -> fused pooled K+V path, z-split;
// blocks 256..767 -> Q path (LDS-staged MFMA).
// Layouts: Qb[b][t][32], Kt[b][s][32], Vb[b][ch][4096].
// ---------------------------------------------------------------------------
__global__ __launch_bounds__(256) void proj_kernel(
    const float* __restrict__ x, const float* __restrict__ Wq, const float* __restrict__ bq,
    const float* __restrict__ Wk, const float* __restrict__ bk, const float* __restrict__ Wv,
    const float* __restrict__ bv, u16* __restrict__ Qb, u16* __restrict__ Kt,
    u16* __restrict__ Vb) {
  __shared__ __align__(16) u16 smem[24576];  // 48KB: xt(32KB)+wq(16KB) | xs(32KB)
  const int tid = threadIdx.x;
  const int lane = tid & 63, w = tid >> 6;
  const int l15 = lane & 15, l4 = lane >> 4;
  const int bi = blockIdx.x;
  const f32x4 zero = {0.f, 0.f, 0.f, 0.f};

  if (bi >= 256) {
    // ================= Q path (verified, LDS-staged) =================
    u16* xt = smem;          // [64 t][256 c] bf16, swizzled
    u16* wq = smem + 16384;  // [32 oc][256 c] bf16, swizzled, pre-scaled
    const int j = bi - 256;
    const int b = j >> 8, tb = j & 255;
    const float* xp = x + (size_t)b * 256 * 16384 + tb * 64;

    for (int i = tid; i < 4096; i += 256) {
      int oc = i >> 7, c0 = (i & 127) * 2;
      float2 f = *reinterpret_cast<const float2*>(Wq + oc * 256 + c0);
      u32 pk = cvt_pk_bf16(f.x * QSCALE, f.y * QSCALE);
      *reinterpret_cast<u32*>((char*)wq + oc * 512 + (((c0 >> 3) ^ (oc & 7)) * 16) +
                              (c0 & 7) * 2) = pk;
    }
#pragma unroll
    for (int rr = 0; rr < 4; ++rr) {
      int c = rr * 64 + (tid >> 2);
      int tch = (tid & 3) * 16;
      const float* src = xp + (size_t)c * 16384 + tch;
#pragma unroll
      for (int u = 0; u < 4; ++u) {
        float4 f = *reinterpret_cast<const float4*>(src + u * 4);
        int t = tch + u * 4;
        *reinterpret_cast<u16*>((char*)xt + (t + 0) * 512 + (((c >> 3) ^ ((t + 0) & 7)) * 16) + (c & 7) * 2) = f2bf(f.x);
        *reinterpret_cast<u16*>((char*)xt + (t + 1) * 512 + (((c >> 3) ^ ((t + 1) & 7)) * 16) + (c & 7) * 2) = f2bf(f.y);
        *reinterpret_cast<u16*>((char*)xt + (t + 2) * 512 + (((c >> 3) ^ ((t + 2) & 7)) * 16) + (c & 7) * 2) = f2bf(f.z);
        *reinterpret_cast<u16*>((char*)xt + (t + 3) * 512 + (((c >> 3) ^ ((t + 3) & 7)) * 16) + (c & 7) * 2) = f2bf(f.w);
      }
    }
    __syncthreads();

    f32x4 acc[2] = {zero, zero};
    const int tl = w * 16 + l15;
#pragma unroll
    for (int k = 0; k < 8; ++k) {
      bf16x8 bf = *reinterpret_cast<const bf16x8*>((char*)xt + tl * 512 +
                                                   (((k * 4 + l4) ^ (tl & 7)) * 16));
#pragma unroll
      for (int m = 0; m < 2; ++m) {
        int oc = m * 16 + l15;
        bf16x8 af = *reinterpret_cast<const bf16x8*>((char*)wq + oc * 512 +
                                                     (((k * 4 + l4) ^ (oc & 7)) * 16));
        acc[m] = __builtin_amdgcn_mfma_f32_16x16x32_bf16(af, bf, acc[m], 0, 0, 0);
      }
    }
    const int t = tb * 64 + tl;
#pragma unroll
    for (int m = 0; m < 2; ++m) {
      int oc0 = m * 16 + l4 * 4;
      u32 p0 = cvt_pk_bf16(acc[m][0] + bq[oc0] * QSCALE, acc[m][1] + bq[oc0 + 1] * QSCALE);
      u32 p1 = cvt_pk_bf16(acc[m][2] + bq[oc0 + 2] * QSCALE, acc[m][3] + bq[oc0 + 3] * QSCALE);
      u16* dst = Qb + ((size_t)b * 16384 + t) * 32 + oc0;
      *reinterpret_cast<u32*>(dst) = p0;
      *reinterpret_cast<u32*>(dst + 2) = p1;
    }
  } else {
    // ================= fused K+V path, z-split =================
    u16* xs = smem;  // pooled [64 s][256 c] bf16, swizzled
    const int b = bi >> 7, r2 = bi & 127;
    const int sy = r2 >> 1, z = r2 & 1;
    const int mb = z * 8;
    const float* xb = x + (size_t)b * 256 * 16384;

#pragma unroll
    for (int rr = 0; rr < 4; ++rr) {
      int c = rr * 64 + (tid >> 2);
      int f4base = (tid & 3) * 8;
      const float* r0 = xb + (size_t)c * 16384 + (size_t)sy * 256;
#pragma unroll
      for (int u = 0; u < 8; ++u) {
        int jj = f4base + u;
        float4 a = *reinterpret_cast<const float4*>(r0 + jj * 4);
        float4 d = *reinterpret_cast<const float4*>(r0 + 128 + jj * 4);
        float p0 = (a.x + a.y + d.x + d.y) * 0.25f;
        float p1 = (a.z + a.w + d.z + d.w) * 0.25f;
        int s0 = jj * 2;
        *reinterpret_cast<u16*>((char*)xs + (s0 + 0) * 512 + (((c >> 3) ^ ((s0 + 0) & 7)) * 16) + (c & 7) * 2) = f2bf(p0);
        *reinterpret_cast<u16*>((char*)xs + (s0 + 1) * 512 + (((c >> 3) ^ ((s0 + 1) & 7)) * 16) + (c & 7) * 2) = f2bf(p1);
      }
    }
    __syncthreads();

    f32x4 acc[10];
#pragma unroll
    for (int m = 0; m < 10; ++m) acc[m] = zero;
    const int sl = w * 16 + l15;
#pragma unroll
    for (int k = 0; k < 8; ++k) {
      bf16x8 bf = *reinterpret_cast<const bf16x8*>((char*)xs + sl * 512 +
                                                   (((k * 4 + l4) ^ (sl & 7)) * 16));
      if (z == 0) {
#pragma unroll
        for (int m = 0; m < 2; ++m) {
          const float* wr = Wk + (size_t)(m * 16 + l15) * 256 + k * 32 + l4 * 8;
          float4 fa = *reinterpret_cast<const float4*>(wr);
          float4 fb = *reinterpret_cast<const float4*>(wr + 4);
          acc[m] = __builtin_amdgcn_mfma_f32_16x16x32_bf16(f32x8_to_bf16x8(fa, fb), bf, acc[m], 0, 0, 0);
        }
      }
#pragma unroll
      for (int mm = 0; mm < 8; ++mm) {
        const float* wr = Wv + (size_t)((mb + mm) * 16 + l15) * 256 + k * 32 + l4 * 8;
        float4 fa = *reinterpret_cast<const float4*>(wr);
        float4 fb = *reinterpret_cast<const float4*>(wr + 4);
        acc[2 + mm] = __builtin_amdgcn_mfma_f32_16x16x32_bf16(f32x8_to_bf16x8(fa, fb), bf, acc[2 + mm], 0, 0, 0);
      }
    }
    if (z == 0) {
#pragma unroll
      for (int m = 0; m < 2; ++m) {
        int oc0 = m * 16 + l4 * 4;
        u32 p0 = cvt_pk_bf16(acc[m][0] + bk[oc0], acc[m][1] + bk[oc0 + 1]);
        u32 p1 = cvt_pk_bf16(acc[m][2] + bk[oc0 + 2], acc[m][3] + bk[oc0 + 3]);
        u16* dst = Kt + ((size_t)b * 4096 + sy * 64 + sl) * 32 + oc0;
        *reinterpret_cast<u32*>(dst) = p0;
        *reinterpret_cast<u32*>(dst + 2) = p1;
      }
    }
#pragma unroll
    for (int mm = 0; mm < 8; ++mm) {
#pragma unroll
      for (int r = 0; r < 4; ++r) {
        int oc = (mb + mm) * 16 + l4 * 4 + r;
        Vb[((size_t)b * 256 + oc) * 4096 + sy * 64 + sl] = f2bf(acc[2 + mm][r] + bv[oc]);
      }
    }
  }
}

// ---------------------------------------------------------------------------
// attn v16 = R14 verbatim (session-best verified): block 256thr/4 waves,
// 64tok x 256ch; wave QK = 16-key strip x 64 tok (no duplication); PV =
// 64tok x 64ch quadrant (mt=4,nt=4, 0.5KB LDS/MFMA); LDS 80KB = p_lds dbuf
// 2x8KB + v_lds dbuf 2x32KB; ONE barrier/iter, no exposed DMA drain;
// logit clamp + immediate P-write (both mandatory — R13 lesson);
// K reg-dbuf prefetch; setprio around PV; XCD swizzle.
// ---------------------------------------------------------------------------
__global__ __launch_bounds__(256, 2) void attn_kernel(
    const u16* __restrict__ Qb, const u16* __restrict__ Kt, const u16* __restrict__ Vb,
    const float* __restrict__ x, const float* __restrict__ gamma, float* __restrict__ out) {
  __shared__ __align__(16) u16 p_lds[2][64 * 64];   // 16KB dbuf P [tok][key swz]
  __shared__ __align__(16) u16 v_lds[2][256 * 64];  // 64KB dbuf V [ch][key swz]

  const int tid = threadIdx.x;
  const int lane = tid & 63, w = tid >> 6;
  const int l15 = lane & 15, l4 = lane >> 4, l7 = l15 & 7;
  const int raw = blockIdx.x;               // 0..511
  const int xcd = raw & 7, loc = raw >> 3;  // loc 0..63
  const int b = xcd >> 2;
  const int tt = (xcd & 3) * 64 + loc;      // tok-tile 0..255
  const int t0 = tt * 64;

  const u16* Qp = Qb + (size_t)(b * 16384 + t0) * 32;
  const char* Kpc = (const char*)(Kt + (size_t)b * 4096 * 32);
  const char* Vpc = (const char*)(Vb + (size_t)b * 256 * 4096);

  // Q fragments (loop-invariant): B-op col = tok = mt*16+l15, k-chunk l4
  bf16x8 qfr[4];
#pragma unroll
  for (int mt = 0; mt < 4; ++mt)
    qfr[mt] = *reinterpret_cast<const bf16x8*>(Qp + (size_t)(mt * 16 + l15) * 32 + l4 * 8);

  const int key = w * 16 + l15;  // QK A-op row (wave's 16-key strip)
  const int pw_chunk = w * 2 + (l4 >> 1), pw_off = (l4 & 1) * 8;

  // ---- loop-invariant lane bases (valid: tok&7 == l7, ch&7 == l7) ----
  char* pA0 = (char*)p_lds + l15 * 128 + ((l4 ^ l7) * 16);
  char* pA1 = (char*)p_lds + l15 * 128 + (((4 ^ l4) ^ l7) * 16);
  char* pW = (char*)p_lds + l15 * 128 + ((pw_chunk ^ l7) * 16) + pw_off;
  char* pV0 = (char*)v_lds + (w * 64 + l15) * 128 + ((l4 ^ l7) * 16);
  char* pV1 = (char*)v_lds + (w * 64 + l15) * 128 + (((4 ^ l4) ^ l7) * 16);

  // ---- staging: per-lane pre-swizzled source (linear dest == swz layout) ----
  const int sch = lane >> 3;         // sub-channel in 8-ch group
  const int skc = (lane & 7) ^ sch;  // source key-chunk
  const u32 vstg0 = (u32)(w * 64 + sch) * 8192 + (u32)skc * 16;  // i stride 65536
  u32 vstg = vstg0 + 128;                               // V(kt=1)
  u32 vok = 2 * 4096 + (u32)key * 64 + (u32)l4 * 16;    // K(kt=2)

  f32x4 acc[4][4] = {};  // [tok mt][ch nt] 64tok x 64ch quadrant
  float lsum[4] = {};
  const f32x4 zero = {0.f, 0.f, 0.f, 0.f};

  // ---- prologue: DMA V(0)->buf0; QK(0)->p_lds[0]; kfrA = K(1) ----
#pragma unroll
  for (int i = 0; i < 8; ++i)
    gload_lds16(Vpc + vstg0 + i * 65536, (u16*)v_lds + (w * 8 + i) * 512);
  {
    bf16x8 k0 = *reinterpret_cast<const bf16x8*>(Kpc + ((size_t)key * 64 + l4 * 16));
#pragma unroll
    for (int mt = 0; mt < 4; ++mt) {
      f32x4 s = __builtin_amdgcn_mfma_f32_16x16x32_bf16(k0, qfr[mt], zero, 0, 0, 0);
      float p0 = exp2_hw(fminf(s[0], 28.f)), p1 = exp2_hw(fminf(s[1], 28.f));
      float p2 = exp2_hw(fminf(s[2], 28.f)), p3 = exp2_hw(fminf(s[3], 28.f));
      lsum[mt] += (p0 + p1) + (p2 + p3);
      *reinterpret_cast<u64*>(pW + mt * 2048) =
          (u64)cvt_pk_bf16(p0, p1) | ((u64)cvt_pk_bf16(p2, p3) << 32);
    }
  }
  bf16x8 kfrA = *reinterpret_cast<const bf16x8*>(Kpc + (4096 + (size_t)key * 64 + l4 * 16));
  bf16x8 kfrB;
  __syncthreads();  // drains V(0) DMA; P(0) visible

#define ATTN_ITER(KT, CUR, KC, KN)                                                        \
  {                                                                                       \
    /* DMA V(KT+1) -> vbuf[CUR^1] at TOP: full iteration of flight time */                \
    if ((KT) < 63) {                                                                      \
      _Pragma("unroll") for (int i = 0; i < 8; ++i)                                       \
          gload_lds16(Vpc + vstg + i * 65536,                                             \
                      (u16*)v_lds + (((CUR) ^ 1) * 16384) + (w * 8 + i) * 512);           \
      vstg += 128;                                                                        \
    }                                                                                     \
    /* ks=0 operand reads (latency hidden under QK/exp below) */                          \
    bf16x8 afr0[4], vfr0[4];                                                              \
    _Pragma("unroll") for (int mt = 0; mt < 4; ++mt)                                      \
        afr0[mt] = *reinterpret_cast<const bf16x8*>(pA0 + ((CUR)*8192 + mt * 2048));      \
    _Pragma("unroll") for (int nt = 0; nt < 4; ++nt)                                      \
        vfr0[nt] = *reinterpret_cast<const bf16x8*>(pV0 + ((CUR)*32768 + nt * 2048));     \
    /* QK(KT+1) + exp + IMMEDIATE packed b64 write P[CUR^1] */                            \
    if ((KT) < 63) {                                                                      \
      _Pragma("unroll") for (int mt = 0; mt < 4; ++mt) {                                  \
        f32x4 s = __builtin_amdgcn_mfma_f32_16x16x32_bf16(KC, qfr[mt], zero, 0, 0, 0);    \
        float p0 = exp2_hw(fminf(s[0], 28.f)), p1 = exp2_hw(fminf(s[1], 28.f));           \
        float p2 = exp2_hw(fminf(s[2], 28.f)), p3 = exp2_hw(fminf(s[3], 28.f));           \
        lsum[mt] += (p0 + p1) + (p2 + p3);                                                \
        *reinterpret_cast<u64*>(pW + (((CUR) ^ 1) * 8192 + mt * 2048)) =                  \
            (u64)cvt_pk_bf16(p0, p1) | ((u64)cvt_pk_bf16(p2, p3) << 32);                  \
      }                                                                                   \
      if ((KT) < 62) { KN = *reinterpret_cast<const bf16x8*>(Kpc + vok); vok += 4096; }   \
    }                                                                                     \
    /* PV(KT): two ks-halves, mt=4 x nt=4 */                                              \
    __builtin_amdgcn_s_setprio(1);                                                        \
    _Pragma("unroll") for (int mt = 0; mt < 4; ++mt)                                      \
      _Pragma("unroll") for (int nt = 0; nt < 4; ++nt)                                    \
        acc[mt][nt] =                                                                     \
            __builtin_amdgcn_mfma_f32_16x16x32_bf16(afr0[mt], vfr0[nt], acc[mt][nt], 0, 0, 0); \
    bf16x8 afr1[4], vfr1[4];                                                              \
    _Pragma("unroll") for (int mt = 0; mt < 4; ++mt)                                      \
        afr1[mt] = *reinterpret_cast<const bf16x8*>(pA1 + ((CUR)*8192 + mt * 2048));      \
    _Pragma("unroll") for (int nt = 0; nt < 4; ++nt)                                      \
        vfr1[nt] = *reinterpret_cast<const bf16x8*>(pV1 + ((CUR)*32768 + nt * 2048));     \
    _Pragma("unroll") for (int mt = 0; mt < 4; ++mt)                                      \
      _Pragma("unroll") for (int nt = 0; nt < 4; ++nt)                                    \
        acc[mt][nt] =                                                                     \
            __builtin_amdgcn_mfma_f32_16x16x32_bf16(afr1[mt], vfr1[nt], acc[mt][nt], 0, 0, 0); \
    __builtin_amdgcn_s_setprio(0);                                                        \
    __syncthreads();                                                                      \
  }

  for (int it = 0; it < 32; ++it) {
    ATTN_ITER(2 * it, 0, kfrA, kfrB)
    ATTN_ITER(2 * it + 1, 1, kfrB, kfrA)
  }
#undef ATTN_ITER

  // ---- row sums: reduce over l4 groups; lred aliased into dead v_lds ----
  float* lred = (float*)v_lds;  // [4 w][64 tok]
#pragma unroll
  for (int mt = 0; mt < 4; ++mt) {
    lsum[mt] += __shfl_xor(lsum[mt], 16, 64);
    lsum[mt] += __shfl_xor(lsum[mt], 32, 64);
  }
  if (l4 == 0) {
#pragma unroll
    for (int mt = 0; mt < 4; ++mt) lred[w * 64 + mt * 16 + l15] = lsum[mt];
  }
  __syncthreads();

  const float g = gamma[0];
  float linv[16];
#pragma unroll
  for (int mt = 0; mt < 4; ++mt)
#pragma unroll
    for (int r = 0; r < 4; ++r) {
      int tok = mt * 16 + l4 * 4 + r;
      linv[mt * 4 + r] =
          1.0f / (lred[tok] + lred[64 + tok] + lred[128 + tok] + lred[192 + tok]);
    }
  // ---- epilogue: out = gamma * acc / l + x ----
#pragma unroll
  for (int mt = 0; mt < 4; ++mt) {
#pragma unroll
    for (int nt = 0; nt < 4; ++nt) {
      int ch = w * 64 + nt * 16 + l15;
      size_t idx = ((size_t)(b * 256 + ch)) * 16384 + t0 + mt * 16 + l4 * 4;
      float4 xr = *reinterpret_cast<const float4*>(x + idx);
      float4 o;
      o.x = g * acc[mt][nt][0] * linv[mt * 4 + 0] + xr.x;
      o.y = g * acc[mt][nt][1] * linv[mt * 4 + 1] + xr.y;
      o.z = g * acc[mt][nt][2] * linv[mt * 4 + 2] + xr.z;
      o.w = g * acc[mt][nt][3] * linv[mt * 4 + 3] + xr.w;
      *reinterpret_cast<float4*>(out + idx) = o;
    }
  }
}

// ---------------------------------------------------------------------------
extern "C" void kernel_launch(void* const* d_in, const int* in_sizes, int n_in,
                              void* d_out, int out_size, void* d_ws, size_t ws_size,
                              hipStream_t stream) {
  const float* x = (const float*)d_in[0];
  const float* Wq = (const float*)d_in[1];
  const float* bq = (const float*)d_in[2];
  const float* Wk = (const float*)d_in[3];
  const float* bk = (const float*)d_in[4];
  const float* Wv = (const float*)d_in[5];
  const float* bv = (const float*)d_in[6];
  const float* gamma = (const float*)d_in[7];
  float* out = (float*)d_out;

  char* ws = (char*)d_ws;
  u16* Qb = (u16*)ws;                                // 2 MB  : [2][16384][32]
  u16* Kt = (u16*)(ws + (2u << 20));                 // 512 KB: [2][4096][32]
  u16* Vb = (u16*)(ws + (2u << 20) + (512u << 10));  // 4 MB  : [2][256][4096]

  proj_kernel<<<dim3(768), 256, 0, stream>>>(x, Wq, bq, Wk, bk, Wv, bv, Qb, Kt, Vb);
  attn_kernel<<<dim3(512), 256, 0, stream>>>(Qb, Kt, Vb, x, gamma, out);
}

// Round 17
// 124.052 us; speedup vs baseline: 1.1850x; 1.0196x over previous
//
#include <hip/hip_runtime.h>

typedef unsigned short u16;
typedef unsigned int u32;
typedef unsigned long long u64;
typedef float f32x4 __attribute__((ext_vector_type(4)));
typedef __bf16 bf16x8 __attribute__((ext_vector_type(8)));

// f32 -> bf16 round-to-nearest-even (scalar)
__device__ __forceinline__ u16 f2bf(float f) {
  unsigned u = __float_as_uint(f);
  unsigned r = u + 0x7fffu + ((u >> 16) & 1u);
  return (u16)(r >> 16);
}
// packed f32 pair -> 2x bf16 in one u32 (lo = first arg)
__device__ __forceinline__ u32 cvt_pk_bf16(float lo, float hi) {
  u32 r;
  asm("v_cvt_pk_bf16_f32 %0, %1, %2" : "=v"(r) : "v"(lo), "v"(hi));
  return r;
}
// hardware 2^x
__device__ __forceinline__ float exp2_hw(float x) {
  float r;
  asm("v_exp_f32 %0, %1" : "=v"(r) : "v"(x));
  return r;
}
// async global->LDS, 16B per lane; dest = uniform base + lane*16 (HW rule)
__device__ __forceinline__ void gload_lds16(const void* g, u16* l) {
  __builtin_amdgcn_global_load_lds(
      (const __attribute__((address_space(1))) unsigned int*)g,
      (__attribute__((address_space(3))) unsigned int*)l, 16, 0, 0);
}

// 1/sqrt(32) * log2(e)  — softmax scale folded with exp->exp2 conversion
#define QSCALE 0.25513936f

// ---------------------------------------------------------------------------
// w_convert: one-shot f32 -> bf16 weight conversion (Wq pre-scaled).
// 40 blocks x 256 thr x 8 elems = 81920 = 8192(Wq) + 8192(Wk) + 65536(Wv).
// ---------------------------------------------------------------------------
__global__ __launch_bounds__(256) void w_convert(
    const float* __restrict__ Wq, const float* __restrict__ Wk, const float* __restrict__ Wv,
    u16* __restrict__ Wqb, u16* __restrict__ Wkb, u16* __restrict__ Wvb) {
  int j = (blockIdx.x * 256 + threadIdx.x) * 8;
  const float* src;
  u16* dst;
  float sc = 1.0f;
  if (j < 8192) {
    src = Wq + j; dst = Wqb + j; sc = QSCALE;
  } else if (j < 16384) {
    src = Wk + (j - 8192); dst = Wkb + (j - 8192);
  } else {
    src = Wv + (j - 16384); dst = Wvb + (j - 16384);
  }
  float4 a = *reinterpret_cast<const float4*>(src);
  float4 b = *reinterpret_cast<const float4*>(src + 4);
  u32 o[4];
  o[0] = cvt_pk_bf16(a.x * sc, a.y * sc);
  o[1] = cvt_pk_bf16(a.z * sc, a.w * sc);
  o[2] = cvt_pk_bf16(b.x * sc, b.y * sc);
  o[3] = cvt_pk_bf16(b.z * sc, b.w * sc);
  *reinterpret_cast<uint4*>(dst) = *reinterpret_cast<uint4*>(o);
}

// ---------------------------------------------------------------------------
// proj_kernel (R7-verified structure; weights now pre-converted bf16):
// blocks 0..255 -> fused pooled K+V path, z-split; blocks 256..767 -> Q path.
// Layouts: Qb[b][t][32], Kt[b][s][32], Vb[b][ch][4096].
// ---------------------------------------------------------------------------
__global__ __launch_bounds__(256) void proj_kernel(
    const float* __restrict__ x, const u16* __restrict__ Wqb, const float* __restrict__ bq,
    const u16* __restrict__ Wkb, const float* __restrict__ bk, const u16* __restrict__ Wvb,
    const float* __restrict__ bv, u16* __restrict__ Qb, u16* __restrict__ Kt,
    u16* __restrict__ Vb) {
  __shared__ __align__(16) u16 smem[24576];  // 48KB: xt(32KB)+wq(16KB) | xs(32KB)
  const int tid = threadIdx.x;
  const int lane = tid & 63, w = tid >> 6;
  const int l15 = lane & 15, l4 = lane >> 4;
  const int bi = blockIdx.x;
  const f32x4 zero = {0.f, 0.f, 0.f, 0.f};

  if (bi >= 256) {
    // ================= Q path (LDS-staged; wq copy from bf16) =================
    u16* xt = smem;          // [64 t][256 c] bf16, swizzled
    u16* wq = smem + 16384;  // [32 oc][256 c] bf16, swizzled, pre-scaled
    const int j = bi - 256;
    const int b = j >> 8, tb = j & 255;
    const float* xp = x + (size_t)b * 256 * 16384 + tb * 64;

    for (int i = tid; i < 4096; i += 256) {
      int oc = i >> 7, c0 = (i & 127) * 2;
      u32 pk = *reinterpret_cast<const u32*>(Wqb + oc * 256 + c0);
      *reinterpret_cast<u32*>((char*)wq + oc * 512 + (((c0 >> 3) ^ (oc & 7)) * 16) +
                              (c0 & 7) * 2) = pk;
    }
#pragma unroll
    for (int rr = 0; rr < 4; ++rr) {
      int c = rr * 64 + (tid >> 2);
      int tch = (tid & 3) * 16;
      const float* src = xp + (size_t)c * 16384 + tch;
#pragma unroll
      for (int u = 0; u < 4; ++u) {
        float4 f = *reinterpret_cast<const float4*>(src + u * 4);
        int t = tch + u * 4;
        *reinterpret_cast<u16*>((char*)xt + (t + 0) * 512 + (((c >> 3) ^ ((t + 0) & 7)) * 16) + (c & 7) * 2) = f2bf(f.x);
        *reinterpret_cast<u16*>((char*)xt + (t + 1) * 512 + (((c >> 3) ^ ((t + 1) & 7)) * 16) + (c & 7) * 2) = f2bf(f.y);
        *reinterpret_cast<u16*>((char*)xt + (t + 2) * 512 + (((c >> 3) ^ ((t + 2) & 7)) * 16) + (c & 7) * 2) = f2bf(f.z);
        *reinterpret_cast<u16*>((char*)xt + (t + 3) * 512 + (((c >> 3) ^ ((t + 3) & 7)) * 16) + (c & 7) * 2) = f2bf(f.w);
      }
    }
    __syncthreads();

    f32x4 acc[2] = {zero, zero};
    const int tl = w * 16 + l15;
#pragma unroll
    for (int k = 0; k < 8; ++k) {
      bf16x8 bf = *reinterpret_cast<const bf16x8*>((char*)xt + tl * 512 +
                                                   (((k * 4 + l4) ^ (tl & 7)) * 16));
#pragma unroll
      for (int m = 0; m < 2; ++m) {
        int oc = m * 16 + l15;
        bf16x8 af = *reinterpret_cast<const bf16x8*>((char*)wq + oc * 512 +
                                                     (((k * 4 + l4) ^ (oc & 7)) * 16));
        acc[m] = __builtin_amdgcn_mfma_f32_16x16x32_bf16(af, bf, acc[m], 0, 0, 0);
      }
    }
    const int t = tb * 64 + tl;
#pragma unroll
    for (int m = 0; m < 2; ++m) {
      int oc0 = m * 16 + l4 * 4;
      u32 p0 = cvt_pk_bf16(acc[m][0] + bq[oc0] * QSCALE, acc[m][1] + bq[oc0 + 1] * QSCALE);
      u32 p1 = cvt_pk_bf16(acc[m][2] + bq[oc0 + 2] * QSCALE, acc[m][3] + bq[oc0 + 3] * QSCALE);
      u16* dst = Qb + ((size_t)b * 16384 + t) * 32 + oc0;
      *reinterpret_cast<u32*>(dst) = p0;
      *reinterpret_cast<u32*>(dst + 2) = p1;
    }
  } else {
    // ================= fused K+V path, z-split (bf16 weights) =================
    u16* xs = smem;  // pooled [64 s][256 c] bf16, swizzled
    const int b = bi >> 7, r2 = bi & 127;
    const int sy = r2 >> 1, z = r2 & 1;
    const int mb = z * 8;
    const float* xb = x + (size_t)b * 256 * 16384;

#pragma unroll
    for (int rr = 0; rr < 4; ++rr) {
      int c = rr * 64 + (tid >> 2);
      int f4base = (tid & 3) * 8;
      const float* r0 = xb + (size_t)c * 16384 + (size_t)sy * 256;
#pragma unroll
      for (int u = 0; u < 8; ++u) {
        int jj = f4base + u;
        float4 a = *reinterpret_cast<const float4*>(r0 + jj * 4);
        float4 d = *reinterpret_cast<const float4*>(r0 + 128 + jj * 4);
        float p0 = (a.x + a.y + d.x + d.y) * 0.25f;
        float p1 = (a.z + a.w + d.z + d.w) * 0.25f;
        int s0 = jj * 2;
        *reinterpret_cast<u16*>((char*)xs + (s0 + 0) * 512 + (((c >> 3) ^ ((s0 + 0) & 7)) * 16) + (c & 7) * 2) = f2bf(p0);
        *reinterpret_cast<u16*>((char*)xs + (s0 + 1) * 512 + (((c >> 3) ^ ((s0 + 1) & 7)) * 16) + (c & 7) * 2) = f2bf(p1);
      }
    }
    __syncthreads();

    f32x4 acc[10];
#pragma unroll
    for (int m = 0; m < 10; ++m) acc[m] = zero;
    const int sl = w * 16 + l15;
#pragma unroll
    for (int k = 0; k < 8; ++k) {
      bf16x8 bf = *reinterpret_cast<const bf16x8*>((char*)xs + sl * 512 +
                                                   (((k * 4 + l4) ^ (sl & 7)) * 16));
      if (z == 0) {
#pragma unroll
        for (int m = 0; m < 2; ++m) {
          bf16x8 af = *reinterpret_cast<const bf16x8*>(Wkb + (size_t)(m * 16 + l15) * 256 +
                                                       k * 32 + l4 * 8);
          acc[m] = __builtin_amdgcn_mfma_f32_16x16x32_bf16(af, bf, acc[m], 0, 0, 0);
        }
      }
#pragma unroll
      for (int mm = 0; mm < 8; ++mm) {
        bf16x8 af = *reinterpret_cast<const bf16x8*>(Wvb + (size_t)((mb + mm) * 16 + l15) * 256 +
                                                     k * 32 + l4 * 8);
        acc[2 + mm] = __builtin_amdgcn_mfma_f32_16x16x32_bf16(af, bf, acc[2 + mm], 0, 0, 0);
      }
    }
    if (z == 0) {
#pragma unroll
      for (int m = 0; m < 2; ++m) {
        int oc0 = m * 16 + l4 * 4;
        u32 p0 = cvt_pk_bf16(acc[m][0] + bk[oc0], acc[m][1] + bk[oc0 + 1]);
        u32 p1 = cvt_pk_bf16(acc[m][2] + bk[oc0 + 2], acc[m][3] + bk[oc0 + 3]);
        u16* dst = Kt + ((size_t)b * 4096 + sy * 64 + sl) * 32 + oc0;
        *reinterpret_cast<u32*>(dst) = p0;
        *reinterpret_cast<u32*>(dst + 2) = p1;
      }
    }
#pragma unroll
    for (int mm = 0; mm < 8; ++mm) {
#pragma unroll
      for (int r = 0; r < 4; ++r) {
        int oc = (mb + mm) * 16 + l4 * 4 + r;
        Vb[((size_t)b * 256 + oc) * 4096 + sy * 64 + sl] = f2bf(acc[2 + mm][r] + bv[oc]);
      }
    }
  }
}

// ---------------------------------------------------------------------------
// attn v17 = R14/R16 VERBATIM (session-best, verified twice): block 256thr/
// 4 waves, 64tok x 256ch; wave QK = 16-key strip x 64 tok; PV = 64tok x 64ch
// quadrant (mt=4,nt=4); LDS 80KB = p_lds dbuf + v_lds dbuf; ONE barrier/iter,
// no exposed DMA drain; logit clamp + immediate P-write; K reg-dbuf prefetch;
// setprio around PV; XCD swizzle.
// ---------------------------------------------------------------------------
__global__ __launch_bounds__(256, 2) void attn_kernel(
    const u16* __restrict__ Qb, const u16* __restrict__ Kt, const u16* __restrict__ Vb,
    const float* __restrict__ x, const float* __restrict__ gamma, float* __restrict__ out) {
  __shared__ __align__(16) u16 p_lds[2][64 * 64];   // 16KB dbuf P [tok][key swz]
  __shared__ __align__(16) u16 v_lds[2][256 * 64];  // 64KB dbuf V [ch][key swz]

  const int tid = threadIdx.x;
  const int lane = tid & 63, w = tid >> 6;
  const int l15 = lane & 15, l4 = lane >> 4, l7 = l15 & 7;
  const int raw = blockIdx.x;               // 0..511
  const int xcd = raw & 7, loc = raw >> 3;  // loc 0..63
  const int b = xcd >> 2;
  const int tt = (xcd & 3) * 64 + loc;      // tok-tile 0..255
  const int t0 = tt * 64;

  const u16* Qp = Qb + (size_t)(b * 16384 + t0) * 32;
  const char* Kpc = (const char*)(Kt + (size_t)b * 4096 * 32);
  const char* Vpc = (const char*)(Vb + (size_t)b * 256 * 4096);

  // Q fragments (loop-invariant): B-op col = tok = mt*16+l15, k-chunk l4
  bf16x8 qfr[4];
#pragma unroll
  for (int mt = 0; mt < 4; ++mt)
    qfr[mt] = *reinterpret_cast<const bf16x8*>(Qp + (size_t)(mt * 16 + l15) * 32 + l4 * 8);

  const int key = w * 16 + l15;  // QK A-op row (wave's 16-key strip)
  const int pw_chunk = w * 2 + (l4 >> 1), pw_off = (l4 & 1) * 8;

  // ---- loop-invariant lane bases (valid: tok&7 == l7, ch&7 == l7) ----
  char* pA0 = (char*)p_lds + l15 * 128 + ((l4 ^ l7) * 16);
  char* pA1 = (char*)p_lds + l15 * 128 + (((4 ^ l4) ^ l7) * 16);
  char* pW = (char*)p_lds + l15 * 128 + ((pw_chunk ^ l7) * 16) + pw_off;
  char* pV0 = (char*)v_lds + (w * 64 + l15) * 128 + ((l4 ^ l7) * 16);
  char* pV1 = (char*)v_lds + (w * 64 + l15) * 128 + (((4 ^ l4) ^ l7) * 16);

  // ---- staging: per-lane pre-swizzled source (linear dest == swz layout) ----
  const int sch = lane >> 3;         // sub-channel in 8-ch group
  const int skc = (lane & 7) ^ sch;  // source key-chunk
  const u32 vstg0 = (u32)(w * 64 + sch) * 8192 + (u32)skc * 16;  // i stride 65536
  u32 vstg = vstg0 + 128;                               // V(kt=1)
  u32 vok = 2 * 4096 + (u32)key * 64 + (u32)l4 * 16;    // K(kt=2)

  f32x4 acc[4][4] = {};  // [tok mt][ch nt] 64tok x 64ch quadrant
  float lsum[4] = {};
  const f32x4 zero = {0.f, 0.f, 0.f, 0.f};

  // ---- prologue: DMA V(0)->buf0; QK(0)->p_lds[0]; kfrA = K(1) ----
#pragma unroll
  for (int i = 0; i < 8; ++i)
    gload_lds16(Vpc + vstg0 + i * 65536, (u16*)v_lds + (w * 8 + i) * 512);
  {
    bf16x8 k0 = *reinterpret_cast<const bf16x8*>(Kpc + ((size_t)key * 64 + l4 * 16));
#pragma unroll
    for (int mt = 0; mt < 4; ++mt) {
      f32x4 s = __builtin_amdgcn_mfma_f32_16x16x32_bf16(k0, qfr[mt], zero, 0, 0, 0);
      float p0 = exp2_hw(fminf(s[0], 28.f)), p1 = exp2_hw(fminf(s[1], 28.f));
      float p2 = exp2_hw(fminf(s[2], 28.f)), p3 = exp2_hw(fminf(s[3], 28.f));
      lsum[mt] += (p0 + p1) + (p2 + p3);
      *reinterpret_cast<u64*>(pW + mt * 2048) =
          (u64)cvt_pk_bf16(p0, p1) | ((u64)cvt_pk_bf16(p2, p3) << 32);
    }
  }
  bf16x8 kfrA = *reinterpret_cast<const bf16x8*>(Kpc + (4096 + (size_t)key * 64 + l4 * 16));
  bf16x8 kfrB;
  __syncthreads();  // drains V(0) DMA; P(0) visible

#define ATTN_ITER(KT, CUR, KC, KN)                                                        \
  {                                                                                       \
    /* DMA V(KT+1) -> vbuf[CUR^1] at TOP: full iteration of flight time */                \
    if ((KT) < 63) {                                                                      \
      _Pragma("unroll") for (int i = 0; i < 8; ++i)                                       \
          gload_lds16(Vpc + vstg + i * 65536,                                             \
                      (u16*)v_lds + (((CUR) ^ 1) * 16384) + (w * 8 + i) * 512);           \
      vstg += 128;                                                                        \
    }                                                                                     \
    /* ks=0 operand reads (latency hidden under QK/exp below) */                          \
    bf16x8 afr0[4], vfr0[4];                                                              \
    _Pragma("unroll") for (int mt = 0; mt < 4; ++mt)                                      \
        afr0[mt] = *reinterpret_cast<const bf16x8*>(pA0 + ((CUR)*8192 + mt * 2048));      \
    _Pragma("unroll") for (int nt = 0; nt < 4; ++nt)                                      \
        vfr0[nt] = *reinterpret_cast<const bf16x8*>(pV0 + ((CUR)*32768 + nt * 2048));     \
    /* QK(KT+1) + exp + IMMEDIATE packed b64 write P[CUR^1] */                            \
    if ((KT) < 63) {                                                                      \
      _Pragma("unroll") for (int mt = 0; mt < 4; ++mt) {                                  \
        f32x4 s = __builtin_amdgcn_mfma_f32_16x16x32_bf16(KC, qfr[mt], zero, 0, 0, 0);    \
        float p0 = exp2_hw(fminf(s[0], 28.f)), p1 = exp2_hw(fminf(s[1], 28.f));           \
        float p2 = exp2_hw(fminf(s[2], 28.f)), p3 = exp2_hw(fminf(s[3], 28.f));           \
        lsum[mt] += (p0 + p1) + (p2 + p3);                                                \
        *reinterpret_cast<u64*>(pW + (((CUR) ^ 1) * 8192 + mt * 2048)) =                  \
            (u64)cvt_pk_bf16(p0, p1) | ((u64)cvt_pk_bf16(p2, p3) << 32);                  \
      }                                                                                   \
      if ((KT) < 62) { KN = *reinterpret_cast<const bf16x8*>(Kpc + vok); vok += 4096; }   \
    }                                                                                     \
    /* PV(KT): two ks-halves, mt=4 x nt=4 */                                              \
    __builtin_amdgcn_s_setprio(1);                                                        \
    _Pragma("unroll") for (int mt = 0; mt < 4; ++mt)                                      \
      _Pragma("unroll") for (int nt = 0; nt < 4; ++nt)                                    \
        acc[mt][nt] =                                                                     \
            __builtin_amdgcn_mfma_f32_16x16x32_bf16(afr0[mt], vfr0[nt], acc[mt][nt], 0, 0, 0); \
    bf16x8 afr1[4], vfr1[4];                                                              \
    _Pragma("unroll") for (int mt = 0; mt < 4; ++mt)                                      \
        afr1[mt] = *reinterpret_cast<const bf16x8*>(pA1 + ((CUR)*8192 + mt * 2048));      \
    _Pragma("unroll") for (int nt = 0; nt < 4; ++nt)                                      \
        vfr1[nt] = *reinterpret_cast<const bf16x8*>(pV1 + ((CUR)*32768 + nt * 2048));     \
    _Pragma("unroll") for (int mt = 0; mt < 4; ++mt)                                      \
      _Pragma("unroll") for (int nt = 0; nt < 4; ++nt)                                    \
        acc[mt][nt] =                                                                     \
            __builtin_amdgcn_mfma_f32_16x16x32_bf16(afr1[mt], vfr1[nt], acc[mt][nt], 0, 0, 0); \
    __builtin_amdgcn_s_setprio(0);                                                        \
    __syncthreads();                                                                      \
  }

  for (int it = 0; it < 32; ++it) {
    ATTN_ITER(2 * it, 0, kfrA, kfrB)
    ATTN_ITER(2 * it + 1, 1, kfrB, kfrA)
  }
#undef ATTN_ITER

  // ---- row sums: reduce over l4 groups; lred aliased into dead v_lds ----
  float* lred = (float*)v_lds;  // [4 w][64 tok]
#pragma unroll
  for (int mt = 0; mt < 4; ++mt) {
    lsum[mt] += __shfl_xor(lsum[mt], 16, 64);
    lsum[mt] += __shfl_xor(lsum[mt], 32, 64);
  }
  if (l4 == 0) {
#pragma unroll
    for (int mt = 0; mt < 4; ++mt) lred[w * 64 + mt * 16 + l15] = lsum[mt];
  }
  __syncthreads();

  const float g = gamma[0];
  float linv[16];
#pragma unroll
  for (int mt = 0; mt < 4; ++mt)
#pragma unroll
    for (int r = 0; r < 4; ++r) {
      int tok = mt * 16 + l4 * 4 + r;
      linv[mt * 4 + r] =
          1.0f / (lred[tok] + lred[64 + tok] + lred[128 + tok] + lred[192 + tok]);
    }
  // ---- epilogue: out = gamma * acc / l + x ----
#pragma unroll
  for (int mt = 0; mt < 4; ++mt) {
#pragma unroll
    for (int nt = 0; nt < 4; ++nt) {
      int ch = w * 64 + nt * 16 + l15;
      size_t idx = ((size_t)(b * 256 + ch)) * 16384 + t0 + mt * 16 + l4 * 4;
      float4 xr = *reinterpret_cast<const float4*>(x + idx);
      float4 o;
      o.x = g * acc[mt][nt][0] * linv[mt * 4 + 0] + xr.x;
      o.y = g * acc[mt][nt][1] * linv[mt * 4 + 1] + xr.y;
      o.z = g * acc[mt][nt][2] * linv[mt * 4 + 2] + xr.z;
      o.w = g * acc[mt][nt][3] * linv[mt * 4 + 3] + xr.w;
      *reinterpret_cast<float4*>(out + idx) = o;
    }
  }
}

// ---------------------------------------------------------------------------
extern "C" void kernel_launch(void* const* d_in, const int* in_sizes, int n_in,
                              void* d_out, int out_size, void* d_ws, size_t ws_size,
                              hipStream_t stream) {
  const float* x = (const float*)d_in[0];
  const float* Wq = (const float*)d_in[1];
  const float* bq = (const float*)d_in[2];
  const float* Wk = (const float*)d_in[3];
  const float* bk = (const float*)d_in[4];
  const float* Wv = (const float*)d_in[5];
  const float* bv = (const float*)d_in[6];
  const float* gamma = (const float*)d_in[7];
  float* out = (float*)d_out;

  char* ws = (char*)d_ws;
  u16* Qb = (u16*)ws;                                        // 2 MB  : [2][16384][32]
  u16* Kt = (u16*)(ws + (2u << 20));                         // 512 KB: [2][4096][32]
  u16* Vb = (u16*)(ws + (2u << 20) + (512u << 10));          // 4 MB  : [2][256][4096]
  u16* Wqb = (u16*)(ws + (6u << 20) + (512u << 10));         // 16 KB : [32][256]
  u16* Wkb = Wqb + 8192;                                     // 16 KB : [32][256]
  u16* Wvb = Wkb + 8192;                                     // 128 KB: [256][256]

  w_convert<<<dim3(40), 256, 0, stream>>>(Wq, Wk, Wv, Wqb, Wkb, Wvb);
  proj_kernel<<<dim3(768), 256, 0, stream>>>(x, Wqb, bq, Wkb, bk, Wvb, bv, Qb, Kt, Vb);
  attn_kernel<<<dim3(512), 256, 0, stream>>>(Qb, Kt, Vb, x, gamma, out);
}